// Round 2
// baseline (36.181 us; speedup 1.0000x reference)
//
#include <hip/hip_runtime.h>
#include <math.h>

// Camera projection for 2M gaussians, 4 points/thread, all-float4 I/O.
// Output layout (flat f32): pos2d[N*3] | cov2d[N*4] | mask[N]

__global__ __launch_bounds__(256) void camera_kernel4(
    const float* __restrict__ pos3d,   // (N,3)
    const float* __restrict__ cov3d,   // (N,3,3)
    const float* __restrict__ w2m,     // (4,4)
    float* __restrict__ pos2d,         // (N,3)
    float* __restrict__ cov2d,         // (N,2,2)
    float* __restrict__ maskf,         // (N,)
    int n, float fx, float fy, float pA, float pB)
{
    const int t = blockIdx.x * blockDim.x + threadIdx.x;
    const int base = t * 4;
    if (base >= n) return;

    // Wave-uniform rotation/translation (scalar loads, broadcast).
    const float R00 = w2m[0], R01 = w2m[1], R02 = w2m[2],  t0 = w2m[3];
    const float R10 = w2m[4], R11 = w2m[5], R12 = w2m[6],  t1 = w2m[7];
    const float R20 = w2m[8], R21 = w2m[9], R22 = w2m[10], t2 = w2m[11];

    float p[12];   // 4 points x 3 coords
    float C[36];   // 4 points x 9 cov entries
    float o2[12];  // 4 points x 3 pos2d
    float4 cv[4];
    float mk[4];

    const bool full = (base + 4 <= n);
    if (full) {
        const float4* pp4 = reinterpret_cast<const float4*>(pos3d);
        const float4* cc4 = reinterpret_cast<const float4*>(cov3d);
        #pragma unroll
        for (int q = 0; q < 3; ++q) {
            float4 v = pp4[3 * t + q];
            p[4*q+0] = v.x; p[4*q+1] = v.y; p[4*q+2] = v.z; p[4*q+3] = v.w;
        }
        #pragma unroll
        for (int q = 0; q < 9; ++q) {
            float4 v = cc4[9 * t + q];
            C[4*q+0] = v.x; C[4*q+1] = v.y; C[4*q+2] = v.z; C[4*q+3] = v.w;
        }
    } else {
        #pragma unroll
        for (int j = 0; j < 4; ++j) {
            int i = base + j;
            if (i < n) {
                p[3*j+0] = pos3d[3*i+0]; p[3*j+1] = pos3d[3*i+1]; p[3*j+2] = pos3d[3*i+2];
                #pragma unroll
                for (int q = 0; q < 9; ++q) C[9*j+q] = cov3d[9*i+q];
            } else {
                p[3*j+0] = p[3*j+1] = 0.0f; p[3*j+2] = 1.0f;
                #pragma unroll
                for (int q = 0; q < 9; ++q) C[9*j+q] = 0.0f;
            }
        }
    }

    #pragma unroll
    for (int j = 0; j < 4; ++j) {
        const float x = p[3*j+0], y = p[3*j+1], z = p[3*j+2];

        const float pmx = R00*x + R01*y + R02*z + t0;
        const float pmy = R10*x + R11*y + R12*z + t1;
        const float pmz = R20*x + R21*y + R22*z + t2;

        const float invw = 1.0f / (pmz + 1e-6f);
        const float ndcx = fx * pmx * invw;
        const float ndcy = fy * pmy * invw;
        const float ndcz = (pA * pmz + pB) * invw;

        const bool m = (ndcz >= 0.2f) && (ndcx >= -1.3f) && (ndcx <= 1.3f)
                                      && (ndcy >= -1.3f) && (ndcy <= 1.3f);

        const float px = 0.5f * (ndcx + 1.0f) * 1920.0f;
        const float py = (1.0f - 0.5f * (ndcy + 1.0f)) * 1080.0f;

        o2[3*j+0] = m ? px   : 0.0f;
        o2[3*j+1] = m ? py   : 0.0f;
        o2[3*j+2] = m ? ndcz : 0.0f;

        const float invz = 1.0f / z;
        const float M00 = invz * (R00 - x * R02);
        const float M01 = invz * (R10 - x * R12);
        const float M02 = invz * (R20 - x * R22);
        const float M10 = invz * (R01 - y * R02);
        const float M11 = invz * (R11 - y * R12);
        const float M12 = invz * (R21 - y * R22);

        const float c00 = C[9*j+0], c01 = C[9*j+1], c02 = C[9*j+2];
        const float c10 = C[9*j+3], c11 = C[9*j+4], c12 = C[9*j+5];
        const float c20 = C[9*j+6], c21 = C[9*j+7], c22 = C[9*j+8];

        const float T00 = M00*c00 + M01*c10 + M02*c20;
        const float T01 = M00*c01 + M01*c11 + M02*c21;
        const float T02 = M00*c02 + M01*c12 + M02*c22;
        const float T10 = M10*c00 + M11*c10 + M12*c20;
        const float T11 = M10*c01 + M11*c11 + M12*c21;
        const float T12 = M10*c02 + M11*c12 + M12*c22;

        cv[j].x = m ? (T00*M00 + T01*M01 + T02*M02) : 0.0f;
        cv[j].y = m ? (T00*M10 + T01*M11 + T02*M12) : 0.0f;
        cv[j].z = m ? (T10*M00 + T11*M01 + T12*M02) : 0.0f;
        cv[j].w = m ? (T10*M10 + T11*M11 + T12*M12) : 0.0f;

        mk[j] = m ? 1.0f : 0.0f;
    }

    if (full) {
        float4* po4 = reinterpret_cast<float4*>(pos2d);
        #pragma unroll
        for (int q = 0; q < 3; ++q) {
            float4 v;
            v.x = o2[4*q+0]; v.y = o2[4*q+1]; v.z = o2[4*q+2]; v.w = o2[4*q+3];
            po4[3 * t + q] = v;
        }
        float4* cg4 = reinterpret_cast<float4*>(cov2d);
        #pragma unroll
        for (int j = 0; j < 4; ++j) cg4[4 * t + j] = cv[j];
        float4 mv; mv.x = mk[0]; mv.y = mk[1]; mv.z = mk[2]; mv.w = mk[3];
        reinterpret_cast<float4*>(maskf)[t] = mv;
    } else {
        for (int j = 0; j < 4; ++j) {
            int i = base + j;
            if (i >= n) break;
            pos2d[3*i+0] = o2[3*j+0];
            pos2d[3*i+1] = o2[3*j+1];
            pos2d[3*i+2] = o2[3*j+2];
            cov2d[4*i+0] = cv[j].x; cov2d[4*i+1] = cv[j].y;
            cov2d[4*i+2] = cv[j].z; cov2d[4*i+3] = cv[j].w;
            maskf[i] = mk[j];
        }
    }
}

extern "C" void kernel_launch(void* const* d_in, const int* in_sizes, int n_in,
                              void* d_out, int out_size, void* d_ws, size_t ws_size,
                              hipStream_t stream) {
    const float* pos3d = (const float*)d_in[0];
    const float* cov3d = (const float*)d_in[1];
    const float* w2m   = (const float*)d_in[2];

    const int n = in_sizes[0] / 3;

    float* out   = (float*)d_out;
    float* pos2d = out;                    // n*3
    float* cov2d = out + 3*(size_t)n;      // n*4
    float* maskf = out + 7*(size_t)n;      // n

    const double right = 0.1 * tan(0.5 * 1.2);
    const double top   = 0.1 * tan(0.5 * 0.9);
    const float fx = (float)(2.0 * 0.1 / (2.0 * right));
    const float fy = (float)(2.0 * 0.1 / (2.0 * top));
    const float pA = (float)(100.0 / (100.0 - 0.1));
    const float pB = (float)(-100.0 * 0.1 / (100.0 - 0.1));

    const int block = 256;
    const int pts_per_block = block * 4;
    const int grid = (n + pts_per_block - 1) / pts_per_block;
    camera_kernel4<<<grid, block, 0, stream>>>(pos3d, cov3d, w2m,
                                               pos2d, cov2d, maskf,
                                               n, fx, fy, pA, pB);
}

// Round 3
// 29.680 us; speedup vs baseline: 1.2190x; 1.2190x over previous
//
#include <hip/hip_runtime.h>
#include <math.h>

// Camera projection for 2M gaussians — block-staged LDS version.
// Wave-contiguous float4 global traffic; per-point math reads from LDS.
// Output layout (flat f32): pos2d[N*3] | cov2d[N*4] | mask[N]

#define PTS 256  // points per block == threads per block

__global__ __launch_bounds__(256) void camera_lds(
    const float* __restrict__ pos3d,   // (N,3)
    const float* __restrict__ cov3d,   // (N,3,3)
    const float* __restrict__ w2m,     // (4,4)
    float* __restrict__ pos2d,         // (N,3)
    float* __restrict__ cov2d,         // (N,2,2)
    float* __restrict__ maskf,         // (N,)
    int n, float fx, float fy, float pA, float pB)
{
    __shared__ float4 sp4[PTS * 3 / 4];   // 3 KB  pos3d panel (reused for pos2d out)
    __shared__ float4 sc4[PTS * 9 / 4];   // 9 KB  cov3d panel
    float* spf = reinterpret_cast<float*>(sp4);
    float* scf = reinterpret_cast<float*>(sc4);

    const int tid = threadIdx.x;
    const int b0  = blockIdx.x * PTS;
    const int pc  = min(PTS, n - b0);     // points in this block

    // ---- Phase 1: coalesced global -> LDS staging ----
    {
        const int npos = 3 * pc;
        const float* gp = pos3d + (size_t)3 * b0;     // 16B-aligned (3072B * blockIdx)
        const int nf4 = npos >> 2;
        const float4* gp4 = reinterpret_cast<const float4*>(gp);
        for (int q = tid; q < nf4; q += 256) sp4[q] = gp4[q];
        for (int q = (nf4 << 2) + tid; q < npos; q += 256) spf[q] = gp[q];

        const int ncov = 9 * pc;
        const float* gc = cov3d + (size_t)9 * b0;     // 16B-aligned (9216B * blockIdx)
        const int cf4 = ncov >> 2;
        const float4* gc4 = reinterpret_cast<const float4*>(gc);
        for (int q = tid; q < cf4; q += 256) sc4[q] = gc4[q];
        for (int q = (cf4 << 2) + tid; q < ncov; q += 256) scf[q] = gc[q];
    }
    __syncthreads();

    // ---- Phase 2: per-point registers from LDS ----
    const bool act = (tid < pc);
    const int i = b0 + tid;

    float x = 0.0f, y = 0.0f, z = 1.0f;
    float c00=0,c01=0,c02=0,c10=0,c11=0,c12=0,c20=0,c21=0,c22=0;
    if (act) {
        x = spf[3*tid+0]; y = spf[3*tid+1]; z = spf[3*tid+2];
        c00 = scf[9*tid+0]; c01 = scf[9*tid+1]; c02 = scf[9*tid+2];
        c10 = scf[9*tid+3]; c11 = scf[9*tid+4]; c12 = scf[9*tid+5];
        c20 = scf[9*tid+6]; c21 = scf[9*tid+7]; c22 = scf[9*tid+8];
    }
    __syncthreads();   // all LDS reads done before sp4 is reused for output

    // Wave-uniform rotation/translation.
    const float R00 = w2m[0], R01 = w2m[1], R02 = w2m[2],  t0 = w2m[3];
    const float R10 = w2m[4], R11 = w2m[5], R12 = w2m[6],  t1 = w2m[7];
    const float R20 = w2m[8], R21 = w2m[9], R22 = w2m[10], t2 = w2m[11];

    // ---- Phase 3: math + direct cov2d/mask stores; pos2d into LDS ----
    if (act) {
        const float pmx = R00*x + R01*y + R02*z + t0;
        const float pmy = R10*x + R11*y + R12*z + t1;
        const float pmz = R20*x + R21*y + R22*z + t2;

        const float invw = 1.0f / (pmz + 1e-6f);
        const float ndcx = fx * pmx * invw;
        const float ndcy = fy * pmy * invw;
        const float ndcz = (pA * pmz + pB) * invw;

        const bool m = (ndcz >= 0.2f) && (ndcx >= -1.3f) && (ndcx <= 1.3f)
                                      && (ndcy >= -1.3f) && (ndcy <= 1.3f);

        const float px = 0.5f * (ndcx + 1.0f) * 1920.0f;
        const float py = (1.0f - 0.5f * (ndcy + 1.0f)) * 1080.0f;

        spf[3*tid+0] = m ? px   : 0.0f;
        spf[3*tid+1] = m ? py   : 0.0f;
        spf[3*tid+2] = m ? ndcz : 0.0f;

        const float invz = 1.0f / z;
        const float M00 = invz * (R00 - x * R02);
        const float M01 = invz * (R10 - x * R12);
        const float M02 = invz * (R20 - x * R22);
        const float M10 = invz * (R01 - y * R02);
        const float M11 = invz * (R11 - y * R12);
        const float M12 = invz * (R21 - y * R22);

        const float T00 = M00*c00 + M01*c10 + M02*c20;
        const float T01 = M00*c01 + M01*c11 + M02*c21;
        const float T02 = M00*c02 + M01*c12 + M02*c22;
        const float T10 = M10*c00 + M11*c10 + M12*c20;
        const float T11 = M10*c01 + M11*c11 + M12*c21;
        const float T12 = M10*c02 + M11*c12 + M12*c22;

        float4 cv;
        cv.x = m ? (T00*M00 + T01*M01 + T02*M02) : 0.0f;
        cv.y = m ? (T00*M10 + T01*M11 + T02*M12) : 0.0f;
        cv.z = m ? (T10*M00 + T11*M01 + T12*M02) : 0.0f;
        cv.w = m ? (T10*M10 + T11*M11 + T12*M12) : 0.0f;
        reinterpret_cast<float4*>(cov2d)[i] = cv;   // 16B-aligned, lane-stride 16B

        maskf[i] = m ? 1.0f : 0.0f;                 // contiguous dword store
    }
    __syncthreads();

    // ---- Phase 4: coalesced pos2d store from LDS ----
    {
        const int npos = 3 * pc;
        float* go = pos2d + (size_t)3 * b0;          // 16B-aligned
        const int nf4 = npos >> 2;
        float4* go4 = reinterpret_cast<float4*>(go);
        for (int q = tid; q < nf4; q += 256) go4[q] = sp4[q];
        for (int q = (nf4 << 2) + tid; q < npos; q += 256) go[q] = spf[q];
    }
}

extern "C" void kernel_launch(void* const* d_in, const int* in_sizes, int n_in,
                              void* d_out, int out_size, void* d_ws, size_t ws_size,
                              hipStream_t stream) {
    const float* pos3d = (const float*)d_in[0];
    const float* cov3d = (const float*)d_in[1];
    const float* w2m   = (const float*)d_in[2];

    const int n = in_sizes[0] / 3;

    float* out   = (float*)d_out;
    float* pos2d = out;                    // n*3
    float* cov2d = out + 3*(size_t)n;      // n*4
    float* maskf = out + 7*(size_t)n;      // n

    const double right = 0.1 * tan(0.5 * 1.2);
    const double top   = 0.1 * tan(0.5 * 0.9);
    const float fx = (float)(2.0 * 0.1 / (2.0 * right));
    const float fy = (float)(2.0 * 0.1 / (2.0 * top));
    const float pA = (float)(100.0 / (100.0 - 0.1));
    const float pB = (float)(-100.0 * 0.1 / (100.0 - 0.1));

    const int grid = (n + PTS - 1) / PTS;
    camera_lds<<<grid, 256, 0, stream>>>(pos3d, cov3d, w2m,
                                         pos2d, cov2d, maskf,
                                         n, fx, fy, pA, pB);
}

// Round 4
// 29.520 us; speedup vs baseline: 1.2257x; 1.0054x over previous
//
#include <hip/hip_runtime.h>
#include <math.h>

// Camera projection for 2M gaussians — grid-stride, 4 points/thread.
// Loads keep dense 12B/36B lane strides (proven fine in R1); 48 independent
// loads issued up-front per thread for deep MLP. No LDS, no barriers.
// Output layout (flat f32): pos2d[N*3] | cov2d[N*4] | mask[N]

#define BLK  256
#define ITER 4

__global__ __launch_bounds__(256) void camera_gs(
    const float* __restrict__ pos3d,   // (N,3)
    const float* __restrict__ cov3d,   // (N,3,3)
    const float* __restrict__ w2m,     // (4,4)
    float* __restrict__ pos2d,         // (N,3)
    float* __restrict__ cov2d,         // (N,2,2)
    float* __restrict__ maskf,         // (N,)
    int n, float fx, float fy, float pA, float pB)
{
    const int t0 = blockIdx.x * BLK + threadIdx.x;
    const int G  = gridDim.x * BLK;

    // Wave-uniform rotation/translation (scalar loads, broadcast).
    const float R00 = w2m[0], R01 = w2m[1], R02 = w2m[2],  tr0 = w2m[3];
    const float R10 = w2m[4], R11 = w2m[5], R12 = w2m[6],  tr1 = w2m[7];
    const float R20 = w2m[8], R21 = w2m[9], R22 = w2m[10], tr2 = w2m[11];

    float p[ITER * 3];
    float C[ITER * 9];
    bool  vld[ITER];

    // ---- Issue all loads first (48 independent dword loads in flight) ----
    #pragma unroll
    for (int k = 0; k < ITER; ++k) {
        const int i = t0 + k * G;
        const bool v = (i < n);
        vld[k] = v;
        if (v) {
            p[3*k+0] = pos3d[3*(size_t)i + 0];
            p[3*k+1] = pos3d[3*(size_t)i + 1];
            p[3*k+2] = pos3d[3*(size_t)i + 2];
            #pragma unroll
            for (int q = 0; q < 9; ++q) C[9*k+q] = cov3d[9*(size_t)i + q];
        } else {
            p[3*k+0] = p[3*k+1] = 0.0f; p[3*k+2] = 1.0f;
            #pragma unroll
            for (int q = 0; q < 9; ++q) C[9*k+q] = 0.0f;
        }
    }

    // ---- Compute + store per point ----
    #pragma unroll
    for (int k = 0; k < ITER; ++k) {
        if (!vld[k]) continue;
        const int i = t0 + k * G;

        const float x = p[3*k+0], y = p[3*k+1], z = p[3*k+2];

        const float pmx = R00*x + R01*y + R02*z + tr0;
        const float pmy = R10*x + R11*y + R12*z + tr1;
        const float pmz = R20*x + R21*y + R22*z + tr2;

        const float invw = 1.0f / (pmz + 1e-6f);
        const float ndcx = fx * pmx * invw;
        const float ndcy = fy * pmy * invw;
        const float ndcz = (pA * pmz + pB) * invw;

        const bool m = (ndcz >= 0.2f) && (ndcx >= -1.3f) && (ndcx <= 1.3f)
                                      && (ndcy >= -1.3f) && (ndcy <= 1.3f);

        const float px = 0.5f * (ndcx + 1.0f) * 1920.0f;
        const float py = (1.0f - 0.5f * (ndcy + 1.0f)) * 1080.0f;

        pos2d[3*(size_t)i + 0] = m ? px   : 0.0f;
        pos2d[3*(size_t)i + 1] = m ? py   : 0.0f;
        pos2d[3*(size_t)i + 2] = m ? ndcz : 0.0f;

        const float invz = 1.0f / z;
        const float M00 = invz * (R00 - x * R02);
        const float M01 = invz * (R10 - x * R12);
        const float M02 = invz * (R20 - x * R22);
        const float M10 = invz * (R01 - y * R02);
        const float M11 = invz * (R11 - y * R12);
        const float M12 = invz * (R21 - y * R22);

        const float c00 = C[9*k+0], c01 = C[9*k+1], c02 = C[9*k+2];
        const float c10 = C[9*k+3], c11 = C[9*k+4], c12 = C[9*k+5];
        const float c20 = C[9*k+6], c21 = C[9*k+7], c22 = C[9*k+8];

        const float T00 = M00*c00 + M01*c10 + M02*c20;
        const float T01 = M00*c01 + M01*c11 + M02*c21;
        const float T02 = M00*c02 + M01*c12 + M02*c22;
        const float T10 = M10*c00 + M11*c10 + M12*c20;
        const float T11 = M10*c01 + M11*c11 + M12*c21;
        const float T12 = M10*c02 + M11*c12 + M12*c22;

        float4 cv;
        cv.x = m ? (T00*M00 + T01*M01 + T02*M02) : 0.0f;
        cv.y = m ? (T00*M10 + T01*M11 + T02*M12) : 0.0f;
        cv.z = m ? (T10*M00 + T11*M01 + T12*M02) : 0.0f;
        cv.w = m ? (T10*M10 + T11*M11 + T12*M12) : 0.0f;
        reinterpret_cast<float4*>(cov2d)[i] = cv;

        maskf[i] = m ? 1.0f : 0.0f;
    }
}

extern "C" void kernel_launch(void* const* d_in, const int* in_sizes, int n_in,
                              void* d_out, int out_size, void* d_ws, size_t ws_size,
                              hipStream_t stream) {
    const float* pos3d = (const float*)d_in[0];
    const float* cov3d = (const float*)d_in[1];
    const float* w2m   = (const float*)d_in[2];

    const int n = in_sizes[0] / 3;

    float* out   = (float*)d_out;
    float* pos2d = out;                    // n*3
    float* cov2d = out + 3*(size_t)n;      // n*4
    float* maskf = out + 7*(size_t)n;      // n

    const double right = 0.1 * tan(0.5 * 1.2);
    const double top   = 0.1 * tan(0.5 * 0.9);
    const float fx = (float)(2.0 * 0.1 / (2.0 * right));
    const float fy = (float)(2.0 * 0.1 / (2.0 * top));
    const float pA = (float)(100.0 / (100.0 - 0.1));
    const float pB = (float)(-100.0 * 0.1 / (100.0 - 0.1));

    // 2048 blocks: 8 blocks/CU worth of waves, each thread covers ITER points.
    const int grid = 2048;
    camera_gs<<<grid, BLK, 0, stream>>>(pos3d, cov3d, w2m,
                                        pos2d, cov2d, maskf,
                                        n, fx, fy, pA, pB);
}

// Round 6
// 28.156 us; speedup vs baseline: 1.2850x; 1.0484x over previous
//
#include <hip/hip_runtime.h>
#include <math.h>

// Camera projection for 2M gaussians — R1 structure + nontemporal output
// stores. Outputs are never re-read: nt stores keep them from thrashing the
// L3-resident inputs (steady-state FETCH was 47MB despite 160MB working set
// fitting in 256MB LLC).
// Output layout (flat f32): pos2d[N*3] | cov2d[N*4] | mask[N]

typedef float f32x4 __attribute__((ext_vector_type(4)));

__global__ __launch_bounds__(256) void camera_nt(
    const float* __restrict__ pos3d,   // (N,3)
    const float* __restrict__ cov3d,   // (N,3,3)
    const float* __restrict__ w2m,     // (4,4)
    float* __restrict__ pos2d,         // (N,3)
    float* __restrict__ cov2d,         // (N,2,2)
    float* __restrict__ maskf,         // (N,)
    int n, float fx, float fy, float pA, float pB)
{
    int i = blockIdx.x * blockDim.x + threadIdx.x;
    if (i >= n) return;

    // Wave-uniform rotation/translation (scalar loads, broadcast).
    const float R00 = w2m[0], R01 = w2m[1], R02 = w2m[2],  t0 = w2m[3];
    const float R10 = w2m[4], R11 = w2m[5], R12 = w2m[6],  t1 = w2m[7];
    const float R20 = w2m[8], R21 = w2m[9], R22 = w2m[10], t2 = w2m[11];

    const float x = pos3d[3*(size_t)i + 0];
    const float y = pos3d[3*(size_t)i + 1];
    const float z = pos3d[3*(size_t)i + 2];

    const float pmx = R00*x + R01*y + R02*z + t0;
    const float pmy = R10*x + R11*y + R12*z + t1;
    const float pmz = R20*x + R21*y + R22*z + t2;

    const float invw = 1.0f / (pmz + 1e-6f);
    const float ndcx = fx * pmx * invw;
    const float ndcy = fy * pmy * invw;
    const float ndcz = (pA * pmz + pB) * invw;

    const bool m = (ndcz >= 0.2f) && (ndcx >= -1.3f) && (ndcx <= 1.3f)
                                  && (ndcy >= -1.3f) && (ndcy <= 1.3f);

    const float px = 0.5f * (ndcx + 1.0f) * 1920.0f;
    const float py = (1.0f - 0.5f * (ndcy + 1.0f)) * 1080.0f;

    __builtin_nontemporal_store(m ? px   : 0.0f, &pos2d[3*(size_t)i + 0]);
    __builtin_nontemporal_store(m ? py   : 0.0f, &pos2d[3*(size_t)i + 1]);
    __builtin_nontemporal_store(m ? ndcz : 0.0f, &pos2d[3*(size_t)i + 2]);

    const float invz = 1.0f / z;
    const float M00 = invz * (R00 - x * R02);
    const float M01 = invz * (R10 - x * R12);
    const float M02 = invz * (R20 - x * R22);
    const float M10 = invz * (R01 - y * R02);
    const float M11 = invz * (R11 - y * R12);
    const float M12 = invz * (R21 - y * R22);

    const float c00 = cov3d[9*(size_t)i + 0], c01 = cov3d[9*(size_t)i + 1], c02 = cov3d[9*(size_t)i + 2];
    const float c10 = cov3d[9*(size_t)i + 3], c11 = cov3d[9*(size_t)i + 4], c12 = cov3d[9*(size_t)i + 5];
    const float c20 = cov3d[9*(size_t)i + 6], c21 = cov3d[9*(size_t)i + 7], c22 = cov3d[9*(size_t)i + 8];

    const float T00 = M00*c00 + M01*c10 + M02*c20;
    const float T01 = M00*c01 + M01*c11 + M02*c21;
    const float T02 = M00*c02 + M01*c12 + M02*c22;
    const float T10 = M10*c00 + M11*c10 + M12*c20;
    const float T11 = M10*c01 + M11*c11 + M12*c21;
    const float T12 = M10*c02 + M11*c12 + M12*c22;

    f32x4 cv;
    cv.x = m ? (T00*M00 + T01*M01 + T02*M02) : 0.0f;
    cv.y = m ? (T00*M10 + T01*M11 + T02*M12) : 0.0f;
    cv.z = m ? (T10*M00 + T11*M01 + T12*M02) : 0.0f;
    cv.w = m ? (T10*M10 + T11*M11 + T12*M12) : 0.0f;
    __builtin_nontemporal_store(cv, reinterpret_cast<f32x4*>(cov2d) + i);

    __builtin_nontemporal_store(m ? 1.0f : 0.0f, &maskf[i]);
}

extern "C" void kernel_launch(void* const* d_in, const int* in_sizes, int n_in,
                              void* d_out, int out_size, void* d_ws, size_t ws_size,
                              hipStream_t stream) {
    const float* pos3d = (const float*)d_in[0];
    const float* cov3d = (const float*)d_in[1];
    const float* w2m   = (const float*)d_in[2];

    const int n = in_sizes[0] / 3;

    float* out   = (float*)d_out;
    float* pos2d = out;                    // n*3
    float* cov2d = out + 3*(size_t)n;      // n*4
    float* maskf = out + 7*(size_t)n;      // n

    const double right = 0.1 * tan(0.5 * 1.2);
    const double top   = 0.1 * tan(0.5 * 0.9);
    const float fx = (float)(2.0 * 0.1 / (2.0 * right));
    const float fy = (float)(2.0 * 0.1 / (2.0 * top));
    const float pA = (float)(100.0 / (100.0 - 0.1));
    const float pB = (float)(-100.0 * 0.1 / (100.0 - 0.1));

    const int block = 256;
    const int grid = (n + block - 1) / block;
    camera_nt<<<grid, block, 0, stream>>>(pos3d, cov3d, w2m,
                                          pos2d, cov2d, maskf,
                                          n, fx, fy, pA, pB);
}